// Round 15
// baseline (5338.165 us; speedup 1.0000x reference)
//
#include <hip/hip_runtime.h>
#include <hip/hip_bf16.h>
#include <hip/hip_cooperative_groups.h>
#include <cmath>

namespace cg = cooperative_groups;

#define BB 2
#define TT 4
#define NPATCH 196
#define LL 784            // TT*NPATCH
#define CC 256            // D_MODEL
#define DI 512            // D_INNER
#define NSTATE 16
#define DEPTH 12
#define NCHUNK 49
#define CLEN 16           // NCHUNK*CLEN == LL exactly
#define CTAU 8            // taus per conv block
#define NTOK 1568         // BB*LL
#define MEGA_BLOCKS 400

typedef short short8 __attribute__((ext_vector_type(8)));
typedef float f32x4 __attribute__((ext_vector_type(4)));

__device__ __forceinline__ float sigmoidf_(float x){ return 1.f/(1.f+__expf(-x)); }
__device__ __forceinline__ float siluf_(float x){ return x/(1.f+__expf(-x)); }
__device__ __forceinline__ float softplusf_(float x){ return x > 20.f ? x : log1pf(__expf(x)); }
__device__ __forceinline__ unsigned short f2bf(float f){
  union { float f; unsigned int u; } v; v.f = f;
  unsigned int u = v.u;
  return (unsigned short)((u + 0x7FFFu + ((u>>16)&1u)) >> 16);
}
__device__ __forceinline__ float bf2f(unsigned short u){
  union { unsigned int i; float f; } v; v.i = ((unsigned int)u)<<16; return v.f;
}

// ---------------- mega prep (incl. SS zeroing) ----------------
#define PREP_NA 3072      // cvt in_proj
#define PREP_NB 1536      // cvt out_proj
#define PREP_NC 192       // cvt patch_w
#define PREP_ND 1536      // prep_xp
#define PREP_NF 784       // prebias
#define PREP_NG 4704      // im2col (nTok*3)
#define PREP_NH 80        // zero SS (13*1568 floats)
__global__ void k_prep_all(
    const float* __restrict__ in_proj, unsigned short* __restrict__ WinB,
    const float* __restrict__ out_proj, unsigned short* __restrict__ WoutB,
    const float* __restrict__ patch_w, unsigned short* __restrict__ WpB,
    const float* __restrict__ xpf, const float* __restrict__ xpb, unsigned short* __restrict__ Wxp,
    const float* __restrict__ pb, const float* __restrict__ pos, const float* __restrict__ tpos,
    float* __restrict__ PB,
    const float* __restrict__ x, unsigned short* __restrict__ XCol,
    float* __restrict__ SS)
{
  int blk = blockIdx.x;
  if (blk < PREP_NA + PREP_NB + PREP_NC) {
    const float* src; unsigned short* dst; int i;
    if (blk < PREP_NA)                  { src = in_proj;  dst = WinB;  i = blk*256 + threadIdx.x; }
    else if (blk < PREP_NA + PREP_NB)   { src = out_proj; dst = WoutB; i = (blk-PREP_NA)*256 + threadIdx.x; }
    else                                { src = patch_w;  dst = WpB;   i = (blk-PREP_NA-PREP_NB)*256 + threadIdx.x; }
    float4 v = *(const float4*)(src + (size_t)i*4);
    unsigned short o[4] = { f2bf(v.x), f2bf(v.y), f2bf(v.z), f2bf(v.w) };
    *(uint2*)(dst + (size_t)i*4) = *(uint2*)o;
    return;
  }
  blk -= PREP_NA + PREP_NB + PREP_NC;
  if (blk < PREP_ND) {
    int r = blk & 63; int ld = blk >> 6;
    int layer = ld >> 1, dir = ld & 1;
    const float* src = dir ? xpb : xpf;
    for (int kk = threadIdx.x; kk < 512; kk += 256) {
      float v = (r < 48) ? src[((size_t)layer*48 + r)*512 + kk] : 0.f;
      Wxp[((size_t)blk)*512 + kk] = f2bf(v);
    }
    return;
  }
  blk -= PREP_ND;
  if (blk < PREP_NF) {
    int tp = blk;
    int t = tp / NPATCH, p = tp - t*NPATCH;
    int c = threadIdx.x;
    PB[(size_t)tp*CC + c] = pb[c] + pos[(size_t)p*CC + c] + tpos[(size_t)t*CC + c];
    return;
  }
  blk -= PREP_NF;
  if (blk < PREP_NG) {
    int ci = blk / (BB*LL);
    int row = blk - ci*(BB*LL);
    int b = row / LL, rem = row - b*LL;
    int t = rem / NPATCH, p = rem - t*NPATCH;
    int ph = p / 14, pc = p - ph*14;
    int ii = threadIdx.x >> 4, jj = threadIdx.x & 15;
    float v = x[(((size_t)(b*3+ci)*TT + t)*224 + (ph*16+ii))*224 + (pc*16+jj)];
    XCol[(size_t)row*768 + ci*256 + threadIdx.x] = f2bf(v);
    return;
  }
  blk -= PREP_NG;
  {
    int i = blk*256 + threadIdx.x;
    if (i < 13*BB*LL) SS[i] = 0.f;
  }
}

// ================= device stage functions =================

// GEMM with residual epilogue. unit u: bm=(u%25)*64, bn=(u/25)*64. Nn=CC.
__device__ void dev_gemm_res(
    const unsigned short* __restrict__ Ab, const unsigned short* __restrict__ Ab2,
    const unsigned short* __restrict__ Wb,
    const float* __restrict__ bias, const float* __restrict__ Rold,
    float* __restrict__ Rnew, unsigned short* __restrict__ RnewB,
    float* __restrict__ SS, int K, int u)
{
  __shared__ short As[64][40];
  __shared__ short Bs[64][40];
  int bm = (u % 25)*64, bn = (u / 25)*64;
  int tid = threadIdx.x;
  int wave = tid>>6, lane = tid&63;
  int wm = (wave>>1)*32, wn = (wave&1)*32;
  int quad = lane>>4, l16 = lane&15;
  f32x4 acc[2][2];
  #pragma unroll
  for (int i=0;i<2;i++)
    #pragma unroll
    for (int j=0;j<2;j++){ acc[i][j][0]=0.f; acc[i][j][1]=0.f; acc[i][j][2]=0.f; acc[i][j][3]=0.f; }
  int sr = tid>>2, sc = (tid&3)<<3;
  int gr = bm + sr;
  for (int k0 = 0; k0 < K; k0 += 32) {
    short8 av = {0,0,0,0,0,0,0,0};
    if (gr < NTOK) {
      av = *(const short8*)(Ab + (size_t)gr*K + k0 + sc);
      if (Ab2) {
        short8 a2v = *(const short8*)(Ab2 + (size_t)gr*K + k0 + sc);
        #pragma unroll
        for (int j=0;j<8;j++)
          av[j] = (short)f2bf(bf2f((unsigned short)av[j]) + bf2f((unsigned short)a2v[j]));
      }
    }
    *(short8*)&As[sr][sc] = av;
    *(short8*)&Bs[sr][sc] = *(const short8*)(Wb + (size_t)(bn+sr)*K + k0 + sc);
    __syncthreads();
    short8 a0 = *(const short8*)&As[wm    +l16][quad<<3];
    short8 a1 = *(const short8*)&As[wm+16+l16][quad<<3];
    short8 b0 = *(const short8*)&Bs[wn    +l16][quad<<3];
    short8 b1 = *(const short8*)&Bs[wn+16+l16][quad<<3];
    acc[0][0] = __builtin_amdgcn_mfma_f32_16x16x32_bf16(a0,b0,acc[0][0],0,0,0);
    acc[0][1] = __builtin_amdgcn_mfma_f32_16x16x32_bf16(a0,b1,acc[0][1],0,0,0);
    acc[1][0] = __builtin_amdgcn_mfma_f32_16x16x32_bf16(a1,b0,acc[1][0],0,0,0);
    acc[1][1] = __builtin_amdgcn_mfma_f32_16x16x32_bf16(a1,b1,acc[1][1],0,0,0);
    __syncthreads();
  }
  #pragma unroll
  for (int i=0;i<2;i++){
    #pragma unroll
    for (int r=0;r<4;r++){
      int row = bm + wm + i*16 + quad*4 + r;
      float s = 0.f;
      if (row < NTOK) {
        #pragma unroll
        for (int j=0;j<2;j++){
          int col = bn + wn + j*16 + l16;
          float vv = acc[i][j][r];
          if (bias) vv += bias[(size_t)(row % LL)*CC + col];
          if (Rold) vv += Rold[(size_t)row*CC + col];
          Rnew [(size_t)row*CC + col] = vv;
          RnewB[(size_t)row*CC + col] = f2bf(vv);
          s += vv*vv;
        }
      }
      s += __shfl_xor(s,1); s += __shfl_xor(s,2); s += __shfl_xor(s,4); s += __shfl_xor(s,8);
      if (row < NTOK && l16 == 0) atomicAdd(&SS[row], s);
    }
  }
}

// in_proj GEMM with fused rmsnorm staging. unit u: bm=(u%25)*64, bn=(u/25)*64, Nn=1024.
__device__ void dev_gemm_in(
    const unsigned short* __restrict__ RnewB, const float* __restrict__ SS,
    const float* __restrict__ normw, const unsigned short* __restrict__ Wb,
    unsigned short* __restrict__ Outb, int u)
{
  __shared__ short As[64][40];
  __shared__ short Bs[64][40];
  int bm = (u % 25)*64, bn = (u / 25)*64;
  int tid = threadIdx.x;
  int wave = tid>>6, lane = tid&63;
  int wm = (wave>>1)*32, wn = (wave&1)*32;
  int quad = lane>>4, l16 = lane&15;
  f32x4 acc[2][2];
  #pragma unroll
  for (int i=0;i<2;i++)
    #pragma unroll
    for (int j=0;j<2;j++){ acc[i][j][0]=0.f; acc[i][j][1]=0.f; acc[i][j][2]=0.f; acc[i][j][3]=0.f; }
  int sr = tid>>2, sc = (tid&3)<<3;
  int gr = bm + sr;
  float sc_row = 0.f;
  if (gr < NTOK) sc_row = rsqrtf(SS[gr]*(1.f/CC) + 1e-5f);
  for (int k0 = 0; k0 < CC; k0 += 32) {
    short8 av = {0,0,0,0,0,0,0,0};
    if (gr < NTOK) {
      short8 rb = *(const short8*)(RnewB + (size_t)gr*CC + k0 + sc);
      float4 w0 = *(const float4*)(normw + k0 + sc);
      float4 w1 = *(const float4*)(normw + k0 + sc + 4);
      av[0] = (short)f2bf(bf2f((unsigned short)rb[0]) * sc_row * w0.x);
      av[1] = (short)f2bf(bf2f((unsigned short)rb[1]) * sc_row * w0.y);
      av[2] = (short)f2bf(bf2f((unsigned short)rb[2]) * sc_row * w0.z);
      av[3] = (short)f2bf(bf2f((unsigned short)rb[3]) * sc_row * w0.w);
      av[4] = (short)f2bf(bf2f((unsigned short)rb[4]) * sc_row * w1.x);
      av[5] = (short)f2bf(bf2f((unsigned short)rb[5]) * sc_row * w1.y);
      av[6] = (short)f2bf(bf2f((unsigned short)rb[6]) * sc_row * w1.z);
      av[7] = (short)f2bf(bf2f((unsigned short)rb[7]) * sc_row * w1.w);
    }
    *(short8*)&As[sr][sc] = av;
    *(short8*)&Bs[sr][sc] = *(const short8*)(Wb + (size_t)(bn+sr)*CC + k0 + sc);
    __syncthreads();
    short8 a0 = *(const short8*)&As[wm    +l16][quad<<3];
    short8 a1 = *(const short8*)&As[wm+16+l16][quad<<3];
    short8 b0 = *(const short8*)&Bs[wn    +l16][quad<<3];
    short8 b1 = *(const short8*)&Bs[wn+16+l16][quad<<3];
    acc[0][0] = __builtin_amdgcn_mfma_f32_16x16x32_bf16(a0,b0,acc[0][0],0,0,0);
    acc[0][1] = __builtin_amdgcn_mfma_f32_16x16x32_bf16(a0,b1,acc[0][1],0,0,0);
    acc[1][0] = __builtin_amdgcn_mfma_f32_16x16x32_bf16(a1,b0,acc[1][0],0,0,0);
    acc[1][1] = __builtin_amdgcn_mfma_f32_16x16x32_bf16(a1,b1,acc[1][1],0,0,0);
    __syncthreads();
  }
  #pragma unroll
  for (int i=0;i<2;i++){
    #pragma unroll
    for (int r=0;r<4;r++){
      int row = bm + wm + i*16 + quad*4 + r;
      if (row < NTOK) {
        #pragma unroll
        for (int j=0;j<2;j++){
          int col = bn + wn + j*16 + l16;
          Outb[(size_t)row*1024 + col] = f2bf(acc[i][j][r]);
        }
      }
    }
  }
}

// x_proj GEMM. unit u in [0,50): z=u/25, bm=(u%25)*64.
__device__ void dev_xp(const unsigned short* __restrict__ XSb,
                       const unsigned short* __restrict__ Wxp,
                       float* __restrict__ DBL, int u)
{
  __shared__ short As[64][40];
  __shared__ short Bs[64][40];
  int z = u / 25;
  int bm = (u % 25)*64;
  const unsigned short* A = XSb + (size_t)z*2*LL*DI;
  const unsigned short* W = Wxp + (size_t)z*64*DI;
  int tid = threadIdx.x;
  int wave = tid>>6, lane = tid&63;
  int wm = (wave>>1)*32, wn = (wave&1)*32;
  int quad = lane>>4, l16 = lane&15;
  f32x4 acc[2][2];
  #pragma unroll
  for (int i=0;i<2;i++)
    #pragma unroll
    for (int j=0;j<2;j++){ acc[i][j][0]=0.f; acc[i][j][1]=0.f; acc[i][j][2]=0.f; acc[i][j][3]=0.f; }
  int sr = tid>>2, sc = (tid&3)<<3;
  int gr = bm + sr;
  for (int k0 = 0; k0 < DI; k0 += 32) {
    short8 av = {0,0,0,0,0,0,0,0};
    if (gr < 2*LL) av = *(const short8*)(A + (size_t)gr*DI + k0 + sc);
    *(short8*)&As[sr][sc] = av;
    *(short8*)&Bs[sr][sc] = *(const short8*)(W + (size_t)sr*DI + k0 + sc);
    __syncthreads();
    short8 a0 = *(const short8*)&As[wm    +l16][quad<<3];
    short8 a1 = *(const short8*)&As[wm+16+l16][quad<<3];
    short8 b0 = *(const short8*)&Bs[wn    +l16][quad<<3];
    short8 b1 = *(const short8*)&Bs[wn+16+l16][quad<<3];
    acc[0][0] = __builtin_amdgcn_mfma_f32_16x16x32_bf16(a0,b0,acc[0][0],0,0,0);
    acc[0][1] = __builtin_amdgcn_mfma_f32_16x16x32_bf16(a0,b1,acc[0][1],0,0,0);
    acc[1][0] = __builtin_amdgcn_mfma_f32_16x16x32_bf16(a1,b0,acc[1][0],0,0,0);
    acc[1][1] = __builtin_amdgcn_mfma_f32_16x16x32_bf16(a1,b1,acc[1][1],0,0,0);
    __syncthreads();
  }
  #pragma unroll
  for (int i=0;i<2;i++){
    #pragma unroll
    for (int r=0;r<4;r++){
      int row = bm + wm + i*16 + quad*4 + r;
      if (row < 2*LL) {
        size_t grow = (size_t)z*2*LL + row;
        #pragma unroll
        for (int j=0;j<2;j++){
          int col = wn + j*16 + l16;
          DBL[grow*64 + col] = acc[i][j][r];
        }
      }
    }
  }
}

// conv+silu. unit w in [0,784): dir=w/392; r=w%392; cb=r>>1; dhalf=r&1.
__device__ void dev_conv(const unsigned short* __restrict__ XZb,
    const float* __restrict__ cwf, const float* __restrict__ cbf,
    const float* __restrict__ cwb, const float* __restrict__ cbb,
    unsigned short* __restrict__ XSb, int w)
{
  int dir = w / 392;
  int r = w - dir*392;
  int cbk = r >> 1, dhalf = r & 1;
  int b = cbk / (LL/CTAU), tq = cbk - b*(LL/CTAU);
  int t0 = tq * CTAU;
  const float* cw = dir ? cwb : cwf;
  const float* cb = dir ? cbb : cbf;
  int d = dhalf*256 + threadIdx.x;
  float4 w4 = *(const float4*)(cw + (size_t)d*4);
  float bia = cb[d];
  const unsigned short* xz = XZb + (size_t)b*LL*1024 + d;
  float x0 = 0.f, x1 = 0.f, x2 = 0.f;
  {
    int tt = t0-3; if (tt >= 0) x0 = bf2f(xz[(size_t)(dir ? (LL-1-tt) : tt)*1024]);
    tt = t0-2;     if (tt >= 0) x1 = bf2f(xz[(size_t)(dir ? (LL-1-tt) : tt)*1024]);
    tt = t0-1;     if (tt >= 0) x2 = bf2f(xz[(size_t)(dir ? (LL-1-tt) : tt)*1024]);
  }
  size_t rowbase = ((size_t)(dir*BB + b)*LL + t0)*DI + d;
  #pragma unroll
  for (int i = 0; i < CTAU; ++i) {
    int tt = t0 + i;
    int torig = dir ? (LL-1-tt) : tt;
    float xin = bf2f(xz[(size_t)torig*1024]);
    float acc = bia;
    acc = fmaf(x0, w4.x, acc);
    acc = fmaf(x1, w4.y, acc);
    acc = fmaf(x2, w4.z, acc);
    acc = fmaf(xin, w4.w, acc);
    XSb[rowbase + (size_t)i*DI] = f2bf(siluf_(acc));
    x0 = x1; x1 = x2; x2 = xin;
  }
}

// scan1. unit u in [0,392): chunk=u%49; g=u/49; yhalf=g&1; dirb=g>>1.
__device__ void dev_scan1(const unsigned short* __restrict__ XSb, const float* __restrict__ DBL,
                          const float* __restrict__ dtwf, const float* __restrict__ dtwb,
                          const float* __restrict__ dtbf, const float* __restrict__ dtbb,
                          const float* __restrict__ Alf, const float* __restrict__ Alb,
                          float* __restrict__ Pb, float* __restrict__ Hcb, int u)
{
  __shared__ float Dl[CLEN][NSTATE];
  __shared__ float Bl[CLEN][NSTATE];
  int chunk = u % 49;
  int g = u / 49;
  int yhalf = g & 1, dirb = g >> 1;
  int d = yhalf*256 + threadIdx.x;
  int dir = dirb >> 1;
  const float* Al = dir ? Alb : Alf;
  const float* dtw = dir ? dtwb : dtwf;
  float dtbv = (dir ? dtbb : dtbf)[d];
  float a2[NSTATE], wd[NSTATE];
  {
    const float4* ar = (const float4*)(Al + (size_t)d*NSTATE);
    const float4* wr = (const float4*)(dtw + (size_t)d*NSTATE);
    #pragma unroll
    for (int q=0;q<4;q++){
      float4 v = ar[q];
      a2[q*4+0] = -__expf(v.x)*1.44269504f;
      a2[q*4+1] = -__expf(v.y)*1.44269504f;
      a2[q*4+2] = -__expf(v.z)*1.44269504f;
      a2[q*4+3] = -__expf(v.w)*1.44269504f;
      float4 w = wr[q];
      wd[q*4+0] = w.x; wd[q*4+1] = w.y; wd[q*4+2] = w.z; wd[q*4+3] = w.w;
    }
  }
  {
    int t = threadIdx.x >> 4, s = threadIdx.x & 15;
    size_t row = ((size_t)dirb*LL + chunk*CLEN + t)*64;
    Dl[t][s] = DBL[row + s];
    Bl[t][s] = DBL[row + 16 + s];
  }
  __syncthreads();
  size_t base = (size_t)dirb*LL*DI;
  const unsigned short* xs = XSb + base + (size_t)chunk*CLEN*DI + d;
  float P[NSTATE], h[NSTATE];
  #pragma unroll
  for (int s=0;s<NSTATE;s++){ P[s]=1.f; h[s]=0.f; }
  for (int i = 0; i < CLEN; ++i) {
    float dtv = dtbv;
    #pragma unroll
    for (int rr=0;rr<NSTATE;rr++) dtv = fmaf(Dl[i][rr], wd[rr], dtv);
    float dt = softplusf_(dtv);
    float uu = bf2f(xs[(size_t)i*DI]);
    float du = dt*uu;
    #pragma unroll
    for (int s=0;s<NSTATE;s++){
      float e = exp2f(dt*a2[s]);
      P[s] *= e;
      h[s] = fmaf(e, h[s], du*Bl[i][s]);
    }
  }
  size_t ob = ((size_t)dirb*NCHUNK + chunk)*NSTATE*DI + d;
  #pragma unroll
  for (int s=0;s<NSTATE;s++){
    Pb [ob + (size_t)s*DI] = P[s];
    Hcb[ob + (size_t)s*DI] = h[s];
  }
  __syncthreads();
}

// scan2. unit u in [0,128): dirb=u>>5; i=(u&31)*256+tid.
__device__ void dev_scan2(const float* __restrict__ Pb, float* __restrict__ Hcb, int u)
{
  int dirb = u >> 5;
  int i = (u & 31)*256 + threadIdx.x;
  float h = 0.f;
  for (int c = 0; c < NCHUNK; ++c) {
    size_t idx = ((size_t)dirb*NCHUNK + c)*NSTATE*DI + i;
    float p = Pb[idx], hl = Hcb[idx];
    Hcb[idx] = h;
    h = fmaf(p, h, hl);
  }
}

// scan3. same mapping as scan1.
__device__ void dev_scan3(const unsigned short* __restrict__ XSb, const float* __restrict__ DBL,
                          const unsigned short* __restrict__ XZb,
                          const float* __restrict__ dtwf, const float* __restrict__ dtwb,
                          const float* __restrict__ dtbf, const float* __restrict__ dtbb,
                          const float* __restrict__ Alf, const float* __restrict__ Alb,
                          const float* __restrict__ Dsfp, const float* __restrict__ Dsbp,
                          const float* __restrict__ Hcb, unsigned short* __restrict__ Yb, int u)
{
  __shared__ float Dl3[CLEN][NSTATE];
  __shared__ float BCl[CLEN][32];
  int chunk = u % 49;
  int g = u / 49;
  int yhalf = g & 1, dirb = g >> 1;
  int d = yhalf*256 + threadIdx.x;
  int dir = dirb >> 1, b = dirb & 1;
  const float* Al = dir ? Alb : Alf;
  const float* dtw = dir ? dtwb : dtwf;
  float dtbv = (dir ? dtbb : dtbf)[d];
  float a2[NSTATE], wd[NSTATE];
  {
    const float4* ar = (const float4*)(Al + (size_t)d*NSTATE);
    const float4* wr = (const float4*)(dtw + (size_t)d*NSTATE);
    #pragma unroll
    for (int q=0;q<4;q++){
      float4 v = ar[q];
      a2[q*4+0] = -__expf(v.x)*1.44269504f;
      a2[q*4+1] = -__expf(v.y)*1.44269504f;
      a2[q*4+2] = -__expf(v.z)*1.44269504f;
      a2[q*4+3] = -__expf(v.w)*1.44269504f;
      float4 w = wr[q];
      wd[q*4+0] = w.x; wd[q*4+1] = w.y; wd[q*4+2] = w.z; wd[q*4+3] = w.w;
    }
  }
  {
    int t = threadIdx.x >> 4, s = threadIdx.x & 15;
    size_t row = ((size_t)dirb*LL + chunk*CLEN + t)*64;
    Dl3[t][s] = DBL[row + s];
    BCl[t][s] = DBL[row + 16 + s];
    BCl[t][16+s] = DBL[row + 32 + s];
  }
  __syncthreads();
  float h[NSTATE];
  size_t ob = ((size_t)dirb*NCHUNK + chunk)*NSTATE*DI + d;
  #pragma unroll
  for (int s=0;s<NSTATE;s++) h[s] = Hcb[ob + (size_t)s*DI];
  float Dsv = (dir ? Dsbp : Dsfp)[d];
  size_t base = (size_t)dirb*LL*DI;
  const unsigned short* xs = XSb + base + (size_t)chunk*CLEN*DI + d;
  const unsigned short* zpb = XZb + (size_t)b*LL*1024 + 512 + d;
  unsigned short* y = Yb + base + d;
  for (int i = 0; i < CLEN; ++i) {
    int tau = chunk*CLEN + i;
    float dtv = dtbv;
    #pragma unroll
    for (int rr=0;rr<NSTATE;rr++) dtv = fmaf(Dl3[i][rr], wd[rr], dtv);
    float dt = softplusf_(dtv);
    float uu = bf2f(xs[(size_t)i*DI]);
    float du = dt*uu;
    float yacc = 0.f;
    #pragma unroll
    for (int s=0;s<NSTATE;s++){
      float e = exp2f(dt*a2[s]);
      h[s] = fmaf(e, h[s], du*BCl[i][s]);
      yacc = fmaf(h[s], BCl[i][16+s], yacc);
    }
    int torig = dir ? (LL-1-tau) : tau;
    float zv = bf2f(zpb[(size_t)torig*1024]);
    y[(size_t)torig*DI] = f2bf((yacc + Dsv*uu) * siluf_(zv));
  }
  __syncthreads();
}

// head. unit u in [0,10).
__device__ void dev_head(const float* __restrict__ Rf, const float* __restrict__ nw,
                         const float* __restrict__ bw1, const float* __restrict__ bb1,
                         const float* __restrict__ bw2, const float* __restrict__ bb2,
                         const float* __restrict__ pw1, const float* __restrict__ pb1,
                         const float* __restrict__ pw2, const float* __restrict__ pb2,
                         float* __restrict__ out, int u)
{
  __shared__ float fus[CC], h1[CC];
  __shared__ float sred[4];
  int b = u / 5, j = u % 5;
  int c = threadIdx.x;
  size_t idx = ((size_t)b*LL + j)*CC + c;
  float r = Rf[idx];
  float v = r*r;
  #pragma unroll
  for (int m=1;m<64;m<<=1) v += __shfl_xor(v,m);
  if ((c&63)==0) sred[c>>6]=v;
  __syncthreads();
  float tot = sred[0]+sred[1]+sred[2]+sred[3];
  fus[c] = r * rsqrtf(tot*(1.f/CC)+1e-5f) * nw[c];
  __syncthreads();
  const float* W1 = (j==0) ? bw1 : (pw1 + (size_t)(j-1)*CC*CC);
  const float* B1 = (j==0) ? bb1 : (pb1 + (j-1)*CC);
  float a = B1[c];
  for (int k=0;k<CC;k++) a = fmaf(fus[k], W1[(size_t)c*CC+k], a);
  h1[c] = fmaxf(a, 0.f);
  __syncthreads();
  if (j==0) {
    if (c < 3) {
      float o = bb2[c];
      for (int k=0;k<CC;k++) o = fmaf(h1[k], bw2[c*CC+k], o);
      out[b*11 + c] = o;
    }
  } else {
    if (c < 2) {
      const float* W2 = pw2 + (size_t)((j-1)*2 + c)*CC;
      float o = pb2[(j-1)*2 + c];
      for (int k=0;k<CC;k++) o = fmaf(h1[k], W2[k], o);
      out[b*11 + 3 + (j-1)*2 + c] = sigmoidf_(o);
    }
  }
}

// ================= parameter pack =================
struct MegaParams {
  const unsigned short *WinB, *WoutB, *WpB, *Wxp, *XCol;
  const float *PB;
  const float *convf_w, *convf_b, *convb_w, *convb_b;
  const float *dtf_w, *dtf_b, *dtb_w, *dtb_b;
  const float *A_logf, *A_logb, *Dsf, *Dsb, *norm_w;
  const float *normf_w, *bw1, *bb1, *bw2, *bb2, *pw1, *pb1, *pw2, *pb2;
  float *Rb0, *Rb1, *SS, *DBL, *Pbuf, *Hcb;
  unsigned short *RbB0, *RbB1, *XZb, *XSb, *Yb;
  float *out;
};

// ================= cooperative mega kernel =================
__global__ void k_mega(MegaParams p)
{
  cg::grid_group grid = cg::this_grid();
  // stage 0: patch embed GEMM (seeds residual)
  if (blockIdx.x < 100)
    dev_gemm_res(p.XCol, nullptr, p.WpB, p.PB, nullptr, p.Rb0, p.RbB0, p.SS, 768, blockIdx.x);
  grid.sync();
  for (int layer = 0; layer < DEPTH; ++layer) {
    float* Rold = (layer & 1) ? p.Rb1 : p.Rb0;
    float* Rnew = (layer & 1) ? p.Rb0 : p.Rb1;
    unsigned short* RbOld = (layer & 1) ? p.RbB1 : p.RbB0;
    unsigned short* RbNew = (layer & 1) ? p.RbB0 : p.RbB1;
    dev_gemm_in(RbOld, p.SS + (size_t)layer*NTOK, p.norm_w + layer*CC,
                p.WinB + (size_t)layer*1024*CC, p.XZb, blockIdx.x);
    grid.sync();
    for (int w = blockIdx.x; w < 784; w += gridDim.x)
      dev_conv(p.XZb, p.convf_w + (size_t)layer*DI*4, p.convf_b + (size_t)layer*DI,
               p.convb_w + (size_t)layer*DI*4, p.convb_b + (size_t)layer*DI, p.XSb, w);
    grid.sync();
    if (blockIdx.x < 50)
      dev_xp(p.XSb, p.Wxp + (size_t)layer*2*64*DI, p.DBL, blockIdx.x);
    grid.sync();
    if (blockIdx.x < 392)
      dev_scan1(p.XSb, p.DBL,
                p.dtf_w + (size_t)layer*DI*16, p.dtb_w + (size_t)layer*DI*16,
                p.dtf_b + (size_t)layer*DI, p.dtb_b + (size_t)layer*DI,
                p.A_logf + (size_t)layer*DI*NSTATE, p.A_logb + (size_t)layer*DI*NSTATE,
                p.Pbuf, p.Hcb, blockIdx.x);
    grid.sync();
    if (blockIdx.x < 128)
      dev_scan2(p.Pbuf, p.Hcb, blockIdx.x);
    grid.sync();
    if (blockIdx.x < 392)
      dev_scan3(p.XSb, p.DBL, p.XZb,
                p.dtf_w + (size_t)layer*DI*16, p.dtb_w + (size_t)layer*DI*16,
                p.dtf_b + (size_t)layer*DI, p.dtb_b + (size_t)layer*DI,
                p.A_logf + (size_t)layer*DI*NSTATE, p.A_logb + (size_t)layer*DI*NSTATE,
                p.Dsf + (size_t)layer*DI, p.Dsb + (size_t)layer*DI,
                p.Hcb, p.Yb, blockIdx.x);
    grid.sync();
    if (blockIdx.x < 100)
      dev_gemm_res(p.Yb, p.Yb + (size_t)NTOK*DI, p.WoutB + (size_t)layer*CC*DI,
                   nullptr, Rold, Rnew, RbNew, p.SS + (size_t)(layer+1)*NTOK, DI, blockIdx.x);
    grid.sync();
  }
  if (blockIdx.x < 10)
    dev_head(p.Rb0, p.normf_w, p.bw1, p.bb1, p.bw2, p.bb2,
             p.pw1, p.pb1, p.pw2, p.pb2, p.out, blockIdx.x);
}

// ================= fallback wrappers (identical math, separate dispatches) =================
__global__ void k_w_patch(MegaParams p){ dev_gemm_res(p.XCol, nullptr, p.WpB, p.PB, nullptr, p.Rb0, p.RbB0, p.SS, 768, blockIdx.x); }
__global__ void k_w_in(MegaParams p, int layer){
  const unsigned short* RbOld = (layer & 1) ? p.RbB1 : p.RbB0;
  dev_gemm_in(RbOld, p.SS + (size_t)layer*NTOK, p.norm_w + layer*CC,
              p.WinB + (size_t)layer*1024*CC, p.XZb, blockIdx.x);
}
__global__ void k_w_conv(MegaParams p, int layer){
  dev_conv(p.XZb, p.convf_w + (size_t)layer*DI*4, p.convf_b + (size_t)layer*DI,
           p.convb_w + (size_t)layer*DI*4, p.convb_b + (size_t)layer*DI, p.XSb, blockIdx.x);
}
__global__ void k_w_xp(MegaParams p, int layer){
  dev_xp(p.XSb, p.Wxp + (size_t)layer*2*64*DI, p.DBL, blockIdx.x);
}
__global__ void k_w_scan1(MegaParams p, int layer){
  dev_scan1(p.XSb, p.DBL,
            p.dtf_w + (size_t)layer*DI*16, p.dtb_w + (size_t)layer*DI*16,
            p.dtf_b + (size_t)layer*DI, p.dtb_b + (size_t)layer*DI,
            p.A_logf + (size_t)layer*DI*NSTATE, p.A_logb + (size_t)layer*DI*NSTATE,
            p.Pbuf, p.Hcb, blockIdx.x);
}
__global__ void k_w_scan2(MegaParams p){ dev_scan2(p.Pbuf, p.Hcb, blockIdx.x); }
__global__ void k_w_scan3(MegaParams p, int layer){
  dev_scan3(p.XSb, p.DBL, p.XZb,
            p.dtf_w + (size_t)layer*DI*16, p.dtb_w + (size_t)layer*DI*16,
            p.dtf_b + (size_t)layer*DI, p.dtb_b + (size_t)layer*DI,
            p.A_logf + (size_t)layer*DI*NSTATE, p.A_logb + (size_t)layer*DI*NSTATE,
            p.Dsf + (size_t)layer*DI, p.Dsb + (size_t)layer*DI,
            p.Hcb, p.Yb, blockIdx.x);
}
__global__ void k_w_out(MegaParams p, int layer){
  float* Rold = (layer & 1) ? p.Rb1 : p.Rb0;
  float* Rnew = (layer & 1) ? p.Rb0 : p.Rb1;
  unsigned short* RbNew = (layer & 1) ? p.RbB0 : p.RbB1;
  dev_gemm_res(p.Yb, p.Yb + (size_t)NTOK*DI, p.WoutB + (size_t)layer*CC*DI,
               nullptr, Rold, Rnew, RbNew, p.SS + (size_t)(layer+1)*NTOK, DI, blockIdx.x);
}
__global__ void k_w_head(MegaParams p){
  dev_head(p.Rb0, p.normf_w, p.bw1, p.bb1, p.bw2, p.bb2,
           p.pw1, p.pb1, p.pw2, p.pb2, p.out, blockIdx.x);
}

extern "C" void kernel_launch(void* const* d_in, const int* in_sizes, int n_in,
                              void* d_out, int out_size, void* d_ws, size_t ws_size,
                              hipStream_t stream)
{
  const float* x        = (const float*)d_in[0];
  const float* patch_w  = (const float*)d_in[1];
  const float* patch_b  = (const float*)d_in[2];
  const float* pos      = (const float*)d_in[3];
  const float* tpos     = (const float*)d_in[4];
  const float* in_proj  = (const float*)d_in[5];
  const float* convf_w  = (const float*)d_in[6];
  const float* convf_b  = (const float*)d_in[7];
  const float* xprojf_w = (const float*)d_in[8];
  const float* dtf_w    = (const float*)d_in[9];
  const float* dtf_b    = (const float*)d_in[10];
  const float* A_logf   = (const float*)d_in[11];
  const float* Dsf      = (const float*)d_in[12];
  const float* convb_w  = (const float*)d_in[13];
  const float* convb_b  = (const float*)d_in[14];
  const float* xprojb_w = (const float*)d_in[15];
  const float* dtb_w    = (const float*)d_in[16];
  const float* dtb_b    = (const float*)d_in[17];
  const float* A_logb   = (const float*)d_in[18];
  const float* Dsb      = (const float*)d_in[19];
  const float* out_proj = (const float*)d_in[20];
  const float* norm_w   = (const float*)d_in[21];
  const float* normf_w  = (const float*)d_in[22];
  const float* bbox_w1  = (const float*)d_in[23];
  const float* bbox_b1  = (const float*)d_in[24];
  const float* bbox_w2  = (const float*)d_in[25];
  const float* bbox_b2  = (const float*)d_in[26];
  const float* pix_w1   = (const float*)d_in[27];
  const float* pix_b1   = (const float*)d_in[28];
  const float* pix_w2   = (const float*)d_in[29];
  const float* pix_b2   = (const float*)d_in[30];
  float* out = (float*)d_out;

  float* ws = (float*)d_ws;
  const size_t nTok = (size_t)NTOK;
  float* Rb0 = ws;                 ws += nTok*CC;
  float* Rb1 = ws;                 ws += nTok*CC;
  float* DBL = ws;                 ws += 2*nTok*64;
  float* Pb  = ws;                 ws += (size_t)4*NCHUNK*NSTATE*DI;
  float* Hcb = ws;                 ws += (size_t)4*NCHUNK*NSTATE*DI;
  float* PB  = ws;                 ws += (size_t)LL*CC;
  float* SS  = ws;                 ws += (size_t)(DEPTH+1)*nTok;
  unsigned short* WinB  = (unsigned short*)ws;  ws += (size_t)DEPTH*1024*CC/2;
  unsigned short* WoutB = (unsigned short*)ws;  ws += (size_t)DEPTH*CC*DI/2;
  unsigned short* WpB   = (unsigned short*)ws;  ws += (size_t)CC*768/2;
  unsigned short* XCol  = (unsigned short*)ws;  ws += nTok*768/2;
  unsigned short* RbB0  = (unsigned short*)ws;  ws += nTok*CC/2;
  unsigned short* RbB1  = (unsigned short*)ws;  ws += nTok*CC/2;
  unsigned short* XZb   = (unsigned short*)ws;  ws += nTok*1024/2;
  unsigned short* XSb   = (unsigned short*)ws;  ws += 2*nTok*DI/2;
  unsigned short* Yb    = (unsigned short*)ws;  ws += 2*nTok*DI/2;
  unsigned short* Wxp   = (unsigned short*)ws;  ws += (size_t)DEPTH*2*64*DI/2;
  (void)ws_size; (void)in_sizes; (void)n_in; (void)out_size;

  // all per-call preps (incl. SS zeroing) in one launch
  {
    const unsigned prepBlocks = PREP_NA + PREP_NB + PREP_NC + PREP_ND + PREP_NF + PREP_NG + PREP_NH;
    k_prep_all<<<dim3(prepBlocks), 256, 0, stream>>>(
        in_proj, WinB, out_proj, WoutB, patch_w, WpB,
        xprojf_w, xprojb_w, Wxp,
        patch_b, pos, tpos, PB, x, XCol, SS);
  }

  MegaParams mp;
  mp.WinB = WinB; mp.WoutB = WoutB; mp.WpB = WpB; mp.Wxp = Wxp; mp.XCol = XCol;
  mp.PB = PB;
  mp.convf_w = convf_w; mp.convf_b = convf_b; mp.convb_w = convb_w; mp.convb_b = convb_b;
  mp.dtf_w = dtf_w; mp.dtf_b = dtf_b; mp.dtb_w = dtb_w; mp.dtb_b = dtb_b;
  mp.A_logf = A_logf; mp.A_logb = A_logb; mp.Dsf = Dsf; mp.Dsb = Dsb; mp.norm_w = norm_w;
  mp.normf_w = normf_w; mp.bw1 = bbox_w1; mp.bb1 = bbox_b1; mp.bw2 = bbox_w2; mp.bb2 = bbox_b2;
  mp.pw1 = pix_w1; mp.pb1 = pix_b1; mp.pw2 = pix_w2; mp.pb2 = pix_b2;
  mp.Rb0 = Rb0; mp.Rb1 = Rb1; mp.SS = SS; mp.DBL = DBL; mp.Pbuf = Pb; mp.Hcb = Hcb;
  mp.RbB0 = RbB0; mp.RbB1 = RbB1; mp.XZb = XZb; mp.XSb = XSb; mp.Yb = Yb;
  mp.out = out;

  void* kargs[] = { (void*)&mp };
  hipError_t err = hipLaunchCooperativeKernel((const void*)k_mega, dim3(MEGA_BLOCKS),
                                              dim3(256), kargs, 0, stream);
  if (err != hipSuccess) {
    // fallback: identical math as separate dispatches
    k_w_patch<<<dim3(100), 256, 0, stream>>>(mp);
    for (int i = 0; i < DEPTH; ++i) {
      k_w_in   <<<dim3(400), 256, 0, stream>>>(mp, i);
      k_w_conv <<<dim3(784), 256, 0, stream>>>(mp, i);
      k_w_xp   <<<dim3(50),  256, 0, stream>>>(mp, i);
      k_w_scan1<<<dim3(392), 256, 0, stream>>>(mp, i);
      k_w_scan2<<<dim3(128), 256, 0, stream>>>(mp);
      k_w_scan3<<<dim3(392), 256, 0, stream>>>(mp, i);
      k_w_out  <<<dim3(100), 256, 0, stream>>>(mp, i);
    }
    k_w_head<<<dim3(10), 256, 0, stream>>>(mp);
  }
}

// Round 16
// 1206.358 us; speedup vs baseline: 4.4250x; 4.4250x over previous
//
#include <hip/hip_runtime.h>
#include <hip/hip_bf16.h>
#include <cmath>

#define BB 2
#define TT 4
#define NPATCH 196
#define LL 784            // TT*NPATCH
#define CC 256            // D_MODEL
#define DI 512            // D_INNER
#define NSTATE 16
#define DEPTH 12
#define NCHUNK 49
#define CLEN 16           // NCHUNK*CLEN == LL exactly
#define CTAU 8            // taus per conv block

typedef short short8 __attribute__((ext_vector_type(8)));
typedef float f32x4 __attribute__((ext_vector_type(4)));

__device__ __forceinline__ float sigmoidf_(float x){ return 1.f/(1.f+__expf(-x)); }
__device__ __forceinline__ float siluf_(float x){ return x/(1.f+__expf(-x)); }
__device__ __forceinline__ float softplusf_(float x){ return x > 20.f ? x : log1pf(__expf(x)); }
__device__ __forceinline__ unsigned short f2bf(float f){
  union { float f; unsigned int u; } v; v.f = f;
  unsigned int u = v.u;
  return (unsigned short)((u + 0x7FFFu + ((u>>16)&1u)) >> 16);
}
__device__ __forceinline__ float bf2f(unsigned short u){
  union { unsigned int i; float f; } v; v.i = ((unsigned int)u)<<16; return v.f;
}

// ---------------- mega prep ----------------
#define PREP_NA 3072
#define PREP_NB 1536
#define PREP_NC 192
#define PREP_ND 1536
#define PREP_NF 784
#define PREP_NG 4704      // nTok*3
__global__ void k_prep_all(
    const float* __restrict__ in_proj, unsigned short* __restrict__ WinB,
    const float* __restrict__ out_proj, unsigned short* __restrict__ WoutB,
    const float* __restrict__ patch_w, unsigned short* __restrict__ WpB,
    const float* __restrict__ xpf, const float* __restrict__ xpb, unsigned short* __restrict__ Wxp,
    const float* __restrict__ pb, const float* __restrict__ pos, const float* __restrict__ tpos,
    float* __restrict__ PB,
    const float* __restrict__ x, unsigned short* __restrict__ XCol)
{
  int blk = blockIdx.x;
  if (blk < PREP_NA + PREP_NB + PREP_NC) {
    const float* src; unsigned short* dst; int i;
    if (blk < PREP_NA)                  { src = in_proj;  dst = WinB;  i = blk*256 + threadIdx.x; }
    else if (blk < PREP_NA + PREP_NB)   { src = out_proj; dst = WoutB; i = (blk-PREP_NA)*256 + threadIdx.x; }
    else                                { src = patch_w;  dst = WpB;   i = (blk-PREP_NA-PREP_NB)*256 + threadIdx.x; }
    float4 v = *(const float4*)(src + (size_t)i*4);
    unsigned short o[4] = { f2bf(v.x), f2bf(v.y), f2bf(v.z), f2bf(v.w) };
    *(uint2*)(dst + (size_t)i*4) = *(uint2*)o;
    return;
  }
  blk -= PREP_NA + PREP_NB + PREP_NC;
  if (blk < PREP_ND) {
    int r = blk & 63; int ld = blk >> 6;
    int layer = ld >> 1, dir = ld & 1;
    const float* src = dir ? xpb : xpf;
    for (int kk = threadIdx.x; kk < 512; kk += 256) {
      float v = (r < 48) ? src[((size_t)layer*48 + r)*512 + kk] : 0.f;
      Wxp[((size_t)blk)*512 + kk] = f2bf(v);
    }
    return;
  }
  blk -= PREP_ND;
  if (blk < PREP_NF) {
    int tp = blk;
    int t = tp / NPATCH, p = tp - t*NPATCH;
    int c = threadIdx.x;
    PB[(size_t)tp*CC + c] = pb[c] + pos[(size_t)p*CC + c] + tpos[(size_t)t*CC + c];
    return;
  }
  blk -= PREP_NF;
  {
    int ci = blk / (BB*LL);
    int row = blk - ci*(BB*LL);
    int b = row / LL, rem = row - b*LL;
    int t = rem / NPATCH, p = rem - t*NPATCH;
    int ph = p / 14, pc = p - ph*14;
    int ii = threadIdx.x >> 4, jj = threadIdx.x & 15;
    float v = x[(((size_t)(b*3+ci)*TT + t)*224 + (ph*16+ii))*224 + (pc*16+jj)];
    XCol[(size_t)row*768 + ci*256 + threadIdx.x] = f2bf(v);
  }
}

// ---------------- generic MFMA bf16 GEMM ----------------
__global__ __launch_bounds__(256) void k_gemm_mfma(
    const unsigned short* __restrict__ Ab, const unsigned short* __restrict__ Ab2,
    const unsigned short* __restrict__ Wb,
    float* __restrict__ Out, unsigned short* __restrict__ Outb,
    const float* __restrict__ bias, int M, int Nn, int K)
{
  __shared__ short As[64][40];
  __shared__ short Bs[64][40];
  int bm = blockIdx.x*64, bn = blockIdx.y*64;
  int tid = threadIdx.x;
  int wave = tid>>6, lane = tid&63;
  int wm = (wave>>1)*32, wn = (wave&1)*32;
  int quad = lane>>4, l16 = lane&15;
  f32x4 acc[2][2];
  #pragma unroll
  for (int i=0;i<2;i++)
    #pragma unroll
    for (int j=0;j<2;j++){ acc[i][j][0]=0.f; acc[i][j][1]=0.f; acc[i][j][2]=0.f; acc[i][j][3]=0.f; }
  int sr = tid>>2, sc = (tid&3)<<3;
  int gr = bm + sr;
  for (int k0 = 0; k0 < K; k0 += 32) {
    short8 av = {0,0,0,0,0,0,0,0};
    if (gr < M) {
      av = *(const short8*)(Ab + (size_t)gr*K + k0 + sc);
      if (Ab2) {
        short8 a2v = *(const short8*)(Ab2 + (size_t)gr*K + k0 + sc);
        #pragma unroll
        for (int j=0;j<8;j++)
          av[j] = (short)f2bf(bf2f((unsigned short)av[j]) + bf2f((unsigned short)a2v[j]));
      }
    }
    *(short8*)&As[sr][sc] = av;
    short8 bv = *(const short8*)(Wb + (size_t)(bn+sr)*K + k0 + sc);
    *(short8*)&Bs[sr][sc] = bv;
    __syncthreads();
    short8 a0 = *(const short8*)&As[wm    +l16][quad<<3];
    short8 a1 = *(const short8*)&As[wm+16+l16][quad<<3];
    short8 b0 = *(const short8*)&Bs[wn    +l16][quad<<3];
    short8 b1 = *(const short8*)&Bs[wn+16+l16][quad<<3];
    acc[0][0] = __builtin_amdgcn_mfma_f32_16x16x32_bf16(a0,b0,acc[0][0],0,0,0);
    acc[0][1] = __builtin_amdgcn_mfma_f32_16x16x32_bf16(a0,b1,acc[0][1],0,0,0);
    acc[1][0] = __builtin_amdgcn_mfma_f32_16x16x32_bf16(a1,b0,acc[1][0],0,0,0);
    acc[1][1] = __builtin_amdgcn_mfma_f32_16x16x32_bf16(a1,b1,acc[1][1],0,0,0);
    __syncthreads();
  }
  #pragma unroll
  for (int i=0;i<2;i++){
    #pragma unroll
    for (int r=0;r<4;r++){
      int row = bm + wm + i*16 + quad*4 + r;
      if (row < M) {
        #pragma unroll
        for (int j=0;j<2;j++){
          int col = bn + wn + j*16 + l16;
          float vv = acc[i][j][r];
          if (bias) vv += bias[(size_t)(row % LL)*Nn + col];
          if (Outb) Outb[(size_t)row*Nn + col] = f2bf(vv);
          else      Out [(size_t)row*Nn + col] = vv;
        }
      }
    }
  }
}

// ---------------- x_proj MFMA GEMM: per dir, M=1568, N=64(48 live), K=512 ----------------
__global__ __launch_bounds__(256) void k_gemm_xp(
    const unsigned short* __restrict__ XSb, const unsigned short* __restrict__ Wxp,
    float* __restrict__ DBL)
{
  __shared__ short As[64][40];
  __shared__ short Bs[64][40];
  int z = blockIdx.z;
  int bm = blockIdx.x*64;
  const unsigned short* A = XSb + (size_t)z*2*LL*DI;
  const unsigned short* W = Wxp + (size_t)z*64*DI;
  int tid = threadIdx.x;
  int wave = tid>>6, lane = tid&63;
  int wm = (wave>>1)*32, wn = (wave&1)*32;
  int quad = lane>>4, l16 = lane&15;
  f32x4 acc[2][2];
  #pragma unroll
  for (int i=0;i<2;i++)
    #pragma unroll
    for (int j=0;j<2;j++){ acc[i][j][0]=0.f; acc[i][j][1]=0.f; acc[i][j][2]=0.f; acc[i][j][3]=0.f; }
  int sr = tid>>2, sc = (tid&3)<<3;
  int gr = bm + sr;
  for (int k0 = 0; k0 < DI; k0 += 32) {
    short8 av = {0,0,0,0,0,0,0,0};
    if (gr < 2*LL) av = *(const short8*)(A + (size_t)gr*DI + k0 + sc);
    *(short8*)&As[sr][sc] = av;
    *(short8*)&Bs[sr][sc] = *(const short8*)(W + (size_t)sr*DI + k0 + sc);
    __syncthreads();
    short8 a0 = *(const short8*)&As[wm    +l16][quad<<3];
    short8 a1 = *(const short8*)&As[wm+16+l16][quad<<3];
    short8 b0 = *(const short8*)&Bs[wn    +l16][quad<<3];
    short8 b1 = *(const short8*)&Bs[wn+16+l16][quad<<3];
    acc[0][0] = __builtin_amdgcn_mfma_f32_16x16x32_bf16(a0,b0,acc[0][0],0,0,0);
    acc[0][1] = __builtin_amdgcn_mfma_f32_16x16x32_bf16(a0,b1,acc[0][1],0,0,0);
    acc[1][0] = __builtin_amdgcn_mfma_f32_16x16x32_bf16(a1,b0,acc[1][0],0,0,0);
    acc[1][1] = __builtin_amdgcn_mfma_f32_16x16x32_bf16(a1,b1,acc[1][1],0,0,0);
    __syncthreads();
  }
  #pragma unroll
  for (int i=0;i<2;i++){
    #pragma unroll
    for (int r=0;r<4;r++){
      int row = bm + wm + i*16 + quad*4 + r;
      if (row < 2*LL) {
        size_t grow = (size_t)z*2*LL + row;
        #pragma unroll
        for (int j=0;j<2;j++){
          int col = wn + j*16 + l16;
          DBL[grow*64 + col] = acc[i][j][r];
        }
      }
    }
  }
}

// ---------------- conv1d + silu, 8 taus/block with rolling window ----------------
__global__ void k_conv_silu(const unsigned short* __restrict__ XZb,
    const float* __restrict__ cwf, const float* __restrict__ cbf,
    const float* __restrict__ cwb, const float* __restrict__ cbb,
    unsigned short* __restrict__ XSb)
{
  int dir = blockIdx.z;
  int blk = blockIdx.x;            // b*(LL/CTAU) + t0/CTAU
  int b = blk / (LL/CTAU), tq = blk - b*(LL/CTAU);
  int t0 = tq * CTAU;
  const float* cw = dir ? cwb : cwf;
  const float* cb = dir ? cbb : cbf;
  int d = threadIdx.x;
  float4 w4 = *(const float4*)(cw + (size_t)d*4);
  float bia = cb[d];
  const unsigned short* xz = XZb + (size_t)b*LL*1024 + d;
  float x0 = 0.f, x1 = 0.f, x2 = 0.f;
  {
    int tt = t0-3; if (tt >= 0) x0 = bf2f(xz[(size_t)(dir ? (LL-1-tt) : tt)*1024]);
    tt = t0-2;     if (tt >= 0) x1 = bf2f(xz[(size_t)(dir ? (LL-1-tt) : tt)*1024]);
    tt = t0-1;     if (tt >= 0) x2 = bf2f(xz[(size_t)(dir ? (LL-1-tt) : tt)*1024]);
  }
  size_t rowbase = ((size_t)(dir*BB + b)*LL + t0)*DI + d;
  #pragma unroll
  for (int i = 0; i < CTAU; ++i) {
    int tt = t0 + i;
    int torig = dir ? (LL-1-tt) : tt;
    float xin = bf2f(xz[(size_t)torig*1024]);
    float acc = bia;
    acc = fmaf(x0, w4.x, acc);
    acc = fmaf(x1, w4.y, acc);
    acc = fmaf(x2, w4.z, acc);
    acc = fmaf(xin, w4.w, acc);
    XSb[rowbase + (size_t)i*DI] = f2bf(siluf_(acc));
    x0 = x1; x1 = x2; x2 = xin;
  }
}

// ---------------- residual accumulate + rmsnorm (bf16 out) ----------------
__global__ void k_res_rms(const float* __restrict__ Hin, float* __restrict__ R,
                          unsigned short* __restrict__ Nout, const float* __restrict__ w, int first)
{
  int row = blockIdx.x, c = threadIdx.x;
  size_t idx = (size_t)row*CC + c;
  float h = Hin[idx];
  float r = first ? h : (h + R[idx]);
  R[idx] = r;
  float v = r*r;
  #pragma unroll
  for (int m=1;m<64;m<<=1) v += __shfl_xor(v,m);
  __shared__ float sred[4];
  if ((c & 63)==0) sred[c>>6]=v;
  __syncthreads();
  float tot = sred[0]+sred[1]+sred[2]+sred[3];
  float sc = rsqrtf(tot*(1.f/CC) + 1e-5f);
  Nout[idx] = f2bf(r*sc*w[c]);
}

// ---------------- SSM scan phase 1: local chunk scan with inline dt ----------------
__global__ void k_scan1(const unsigned short* __restrict__ XSb, const float* __restrict__ DBL,
                        const float* __restrict__ dtwf, const float* __restrict__ dtwb,
                        const float* __restrict__ dtbf, const float* __restrict__ dtbb,
                        const float* __restrict__ Alf, const float* __restrict__ Alb,
                        float* __restrict__ Pb, float* __restrict__ Hcb)
{
  int chunk = blockIdx.x;
  int d = blockIdx.y*256 + threadIdx.x;
  int dirb = blockIdx.z;            // dir*2 + b
  int dir = dirb >> 1;
  const float* Al = dir ? Alb : Alf;
  const float* dtw = dir ? dtwb : dtwf;
  float dtbv = (dir ? dtbb : dtbf)[d];
  float a2[NSTATE], wd[NSTATE];
  {
    const float4* ar = (const float4*)(Al + (size_t)d*NSTATE);
    const float4* wr = (const float4*)(dtw + (size_t)d*NSTATE);
    #pragma unroll
    for (int q=0;q<4;q++){
      float4 v = ar[q];
      a2[q*4+0] = -__expf(v.x)*1.44269504f;
      a2[q*4+1] = -__expf(v.y)*1.44269504f;
      a2[q*4+2] = -__expf(v.z)*1.44269504f;
      a2[q*4+3] = -__expf(v.w)*1.44269504f;
      float4 w = wr[q];
      wd[q*4+0] = w.x; wd[q*4+1] = w.y; wd[q*4+2] = w.z; wd[q*4+3] = w.w;
    }
  }
  __shared__ float Dl[CLEN][NSTATE], Bl[CLEN][NSTATE];
  {
    int t = threadIdx.x >> 4, s = threadIdx.x & 15;
    size_t row = ((size_t)dirb*LL + chunk*CLEN + t)*64;
    Dl[t][s] = DBL[row + s];
    Bl[t][s] = DBL[row + 16 + s];
  }
  __syncthreads();
  size_t base = (size_t)dirb*LL*DI;
  const unsigned short* xs = XSb + base + (size_t)chunk*CLEN*DI + d;
  float P[NSTATE], h[NSTATE];
  #pragma unroll
  for (int s=0;s<NSTATE;s++){ P[s]=1.f; h[s]=0.f; }
  for (int i = 0; i < CLEN; ++i) {
    float dtv = dtbv;
    #pragma unroll
    for (int r=0;r<NSTATE;r++) dtv = fmaf(Dl[i][r], wd[r], dtv);
    float dt = softplusf_(dtv);
    float u  = bf2f(xs[(size_t)i*DI]);
    float du = dt*u;
    #pragma unroll
    for (int s=0;s<NSTATE;s++){
      float e = exp2f(dt*a2[s]);
      P[s] *= e;
      h[s] = fmaf(e, h[s], du*Bl[i][s]);
    }
  }
  size_t ob = ((size_t)dirb*NCHUNK + chunk)*NSTATE*DI + d;
  #pragma unroll
  for (int s=0;s<NSTATE;s++){
    Pb [ob + (size_t)s*DI] = P[s];
    Hcb[ob + (size_t)s*DI] = h[s];
  }
}

// ---------------- SSM scan phase 2: carry combine (in place) ----------------
__global__ void k_scan2(const float* __restrict__ Pb, float* __restrict__ Hcb)
{
  int i = blockIdx.x*256 + threadIdx.x;     // s*DI + d
  int dirb = blockIdx.y;
  float h = 0.f;
  for (int c = 0; c < NCHUNK; ++c) {
    size_t idx = ((size_t)dirb*NCHUNK + c)*NSTATE*DI + i;
    float p = Pb[idx], hl = Hcb[idx];
    Hcb[idx] = h;                  // carry-in for chunk c
    h = fmaf(p, h, hl);
  }
}

// ---------------- SSM scan phase 3: re-scan from carry + gate (inline dt) ----------------
__global__ void k_scan3(const unsigned short* __restrict__ XSb, const float* __restrict__ DBL,
                        const unsigned short* __restrict__ XZb,
                        const float* __restrict__ dtwf, const float* __restrict__ dtwb,
                        const float* __restrict__ dtbf, const float* __restrict__ dtbb,
                        const float* __restrict__ Alf, const float* __restrict__ Alb,
                        const float* __restrict__ Dsfp, const float* __restrict__ Dsbp,
                        const float* __restrict__ Hcb, unsigned short* __restrict__ Yb)
{
  int chunk = blockIdx.x;
  int d = blockIdx.y*256 + threadIdx.x;
  int dirb = blockIdx.z;
  int dir = dirb >> 1, b = dirb & 1;
  const float* Al = dir ? Alb : Alf;
  const float* dtw = dir ? dtwb : dtwf;
  float dtbv = (dir ? dtbb : dtbf)[d];
  float a2[NSTATE], wd[NSTATE];
  {
    const float4* ar = (const float4*)(Al + (size_t)d*NSTATE);
    const float4* wr = (const float4*)(dtw + (size_t)d*NSTATE);
    #pragma unroll
    for (int q=0;q<4;q++){
      float4 v = ar[q];
      a2[q*4+0] = -__expf(v.x)*1.44269504f;
      a2[q*4+1] = -__expf(v.y)*1.44269504f;
      a2[q*4+2] = -__expf(v.z)*1.44269504f;
      a2[q*4+3] = -__expf(v.w)*1.44269504f;
      float4 w = wr[q];
      wd[q*4+0] = w.x; wd[q*4+1] = w.y; wd[q*4+2] = w.z; wd[q*4+3] = w.w;
    }
  }
  __shared__ float Dl[CLEN][NSTATE];
  __shared__ float BCl[CLEN][32];
  {
    int t = threadIdx.x >> 4, s = threadIdx.x & 15;
    size_t row = ((size_t)dirb*LL + chunk*CLEN + t)*64;
    Dl[t][s] = DBL[row + s];
    BCl[t][s] = DBL[row + 16 + s];
    BCl[t][16+s] = DBL[row + 32 + s];
  }
  __syncthreads();
  float h[NSTATE];
  size_t ob = ((size_t)dirb*NCHUNK + chunk)*NSTATE*DI + d;
  #pragma unroll
  for (int s=0;s<NSTATE;s++) h[s] = Hcb[ob + (size_t)s*DI];
  float Dsv = (dir ? Dsbp : Dsfp)[d];
  size_t base = (size_t)dirb*LL*DI;
  const unsigned short* xs = XSb + base + (size_t)chunk*CLEN*DI + d;
  const unsigned short* zpb = XZb + (size_t)b*LL*1024 + 512 + d;
  unsigned short* y = Yb + base + d;
  for (int i = 0; i < CLEN; ++i) {
    int tau = chunk*CLEN + i;
    float dtv = dtbv;
    #pragma unroll
    for (int r=0;r<NSTATE;r++) dtv = fmaf(Dl[i][r], wd[r], dtv);
    float dt = softplusf_(dtv);
    float u  = bf2f(xs[(size_t)i*DI]);
    float du = dt*u;
    float yacc = 0.f;
    #pragma unroll
    for (int s=0;s<NSTATE;s++){
      float e = exp2f(dt*a2[s]);
      h[s] = fmaf(e, h[s], du*BCl[i][s]);
      yacc = fmaf(h[s], BCl[i][16+s], yacc);
    }
    int torig = dir ? (LL-1-tau) : tau;
    float zv = bf2f(zpb[(size_t)torig*1024]);
    y[(size_t)torig*DI] = f2bf((yacc + Dsv*u) * siluf_(zv));
  }
}

// ---------------- final heads ----------------
__global__ void k_head(const float* __restrict__ H, const float* __restrict__ R,
                       const float* __restrict__ nw,
                       const float* __restrict__ bw1, const float* __restrict__ bb1,
                       const float* __restrict__ bw2, const float* __restrict__ bb2,
                       const float* __restrict__ pw1, const float* __restrict__ pb1,
                       const float* __restrict__ pw2, const float* __restrict__ pb2,
                       float* __restrict__ out)
{
  int b = blockIdx.x / 5, j = blockIdx.x % 5;
  int c = threadIdx.x;
  __shared__ float fus[CC], h1[CC];
  __shared__ float sred[4];
  size_t idx = ((size_t)b*LL + j)*CC + c;
  float r = H[idx] + R[idx];
  float v = r*r;
  #pragma unroll
  for (int m=1;m<64;m<<=1) v += __shfl_xor(v,m);
  if ((c&63)==0) sred[c>>6]=v;
  __syncthreads();
  float tot = sred[0]+sred[1]+sred[2]+sred[3];
  fus[c] = r * rsqrtf(tot*(1.f/CC)+1e-5f) * nw[c];
  __syncthreads();
  const float* W1 = (j==0) ? bw1 : (pw1 + (size_t)(j-1)*CC*CC);
  const float* B1 = (j==0) ? bb1 : (pb1 + (j-1)*CC);
  float a = B1[c];
  for (int k=0;k<CC;k++) a = fmaf(fus[k], W1[(size_t)c*CC+k], a);
  h1[c] = fmaxf(a, 0.f);
  __syncthreads();
  if (j==0) {
    if (c < 3) {
      float o = bb2[c];
      for (int k=0;k<CC;k++) o = fmaf(h1[k], bw2[c*CC+k], o);
      out[b*11 + c] = o;
    }
  } else {
    if (c < 2) {
      const float* W2 = pw2 + (size_t)((j-1)*2 + c)*CC;
      float o = pb2[(j-1)*2 + c];
      for (int k=0;k<CC;k++) o = fmaf(h1[k], W2[k], o);
      out[b*11 + 3 + (j-1)*2 + c] = sigmoidf_(o);
    }
  }
}

extern "C" void kernel_launch(void* const* d_in, const int* in_sizes, int n_in,
                              void* d_out, int out_size, void* d_ws, size_t ws_size,
                              hipStream_t stream)
{
  const float* x        = (const float*)d_in[0];
  const float* patch_w  = (const float*)d_in[1];
  const float* patch_b  = (const float*)d_in[2];
  const float* pos      = (const float*)d_in[3];
  const float* tpos     = (const float*)d_in[4];
  const float* in_proj  = (const float*)d_in[5];
  const float* convf_w  = (const float*)d_in[6];
  const float* convf_b  = (const float*)d_in[7];
  const float* xprojf_w = (const float*)d_in[8];
  const float* dtf_w    = (const float*)d_in[9];
  const float* dtf_b    = (const float*)d_in[10];
  const float* A_logf   = (const float*)d_in[11];
  const float* Dsf      = (const float*)d_in[12];
  const float* convb_w  = (const float*)d_in[13];
  const float* convb_b  = (const float*)d_in[14];
  const float* xprojb_w = (const float*)d_in[15];
  const float* dtb_w    = (const float*)d_in[16];
  const float* dtb_b    = (const float*)d_in[17];
  const float* A_logb   = (const float*)d_in[18];
  const float* Dsb      = (const float*)d_in[19];
  const float* out_proj = (const float*)d_in[20];
  const float* norm_w   = (const float*)d_in[21];
  const float* normf_w  = (const float*)d_in[22];
  const float* bbox_w1  = (const float*)d_in[23];
  const float* bbox_b1  = (const float*)d_in[24];
  const float* bbox_w2  = (const float*)d_in[25];
  const float* bbox_b2  = (const float*)d_in[26];
  const float* pix_w1   = (const float*)d_in[27];
  const float* pix_b1   = (const float*)d_in[28];
  const float* pix_w2   = (const float*)d_in[29];
  const float* pix_b2   = (const float*)d_in[30];
  float* out = (float*)d_out;

  float* ws = (float*)d_ws;
  const size_t nTok = (size_t)BB*LL;          // 1568
  float* H   = ws;                 ws += nTok*CC;
  float* R   = ws;                 ws += nTok*CC;
  float* DBL = ws;                 ws += 2*nTok*64;
  float* Pb  = ws;                 ws += (size_t)4*NCHUNK*NSTATE*DI;
  float* Hcb = ws;                 ws += (size_t)4*NCHUNK*NSTATE*DI;
  float* PB  = ws;                 ws += (size_t)LL*CC;
  unsigned short* WinB  = (unsigned short*)ws;  ws += (size_t)DEPTH*1024*CC/2;
  unsigned short* WoutB = (unsigned short*)ws;  ws += (size_t)DEPTH*CC*DI/2;
  unsigned short* WpB   = (unsigned short*)ws;  ws += (size_t)CC*768/2;
  unsigned short* XCol  = (unsigned short*)ws;  ws += nTok*768/2;
  unsigned short* NrmB  = (unsigned short*)ws;  ws += nTok*CC/2;
  unsigned short* XZb   = (unsigned short*)ws;  ws += nTok*1024/2;
  unsigned short* XSb   = (unsigned short*)ws;  ws += 2*nTok*DI/2;
  unsigned short* Yb    = (unsigned short*)ws;  ws += 2*nTok*DI/2;
  unsigned short* Wxp   = (unsigned short*)ws;  ws += (size_t)DEPTH*2*64*DI/2;
  (void)ws_size; (void)in_sizes; (void)n_in; (void)out_size;

  // all per-call preps in one launch
  {
    const unsigned prepBlocks = PREP_NA + PREP_NB + PREP_NC + PREP_ND + PREP_NF + PREP_NG;
    k_prep_all<<<dim3(prepBlocks), 256, 0, stream>>>(
        in_proj, WinB, out_proj, WoutB, patch_w, WpB,
        xprojf_w, xprojb_w, Wxp,
        patch_b, pos, tpos, PB, x, XCol);
  }
  k_gemm_mfma<<<dim3(25, 4), 256, 0, stream>>>(XCol, nullptr, WpB, H, nullptr, PB,
                                               (int)nTok, CC, 768);

  for (int i = 0; i < DEPTH; ++i) {
    k_res_rms<<<dim3((unsigned)nTok), 256, 0, stream>>>(H, R, NrmB, norm_w + i*CC, i==0 ? 1 : 0);
    k_gemm_mfma<<<dim3(25, 16), 256, 0, stream>>>(NrmB, nullptr,
        WinB + (size_t)i*1024*CC, nullptr, XZb, nullptr, (int)nTok, 1024, CC);
    k_conv_silu<<<dim3(BB*LL/CTAU, 1, 2), DI, 0, stream>>>(XZb,
        convf_w + (size_t)i*DI*4, convf_b + (size_t)i*DI,
        convb_w + (size_t)i*DI*4, convb_b + (size_t)i*DI, XSb);
    k_gemm_xp<<<dim3(25, 1, 2), 256, 0, stream>>>(XSb,
        Wxp + (size_t)i*2*64*DI, DBL);
    k_scan1<<<dim3(NCHUNK, 2, 4), 256, 0, stream>>>(XSb, DBL,
        dtf_w + (size_t)i*DI*16, dtb_w + (size_t)i*DI*16,
        dtf_b + (size_t)i*DI, dtb_b + (size_t)i*DI,
        A_logf + (size_t)i*DI*NSTATE, A_logb + (size_t)i*DI*NSTATE, Pb, Hcb);
    k_scan2<<<dim3(32, 4), 256, 0, stream>>>(Pb, Hcb);
    k_scan3<<<dim3(NCHUNK, 2, 4), 256, 0, stream>>>(XSb, DBL, XZb,
        dtf_w + (size_t)i*DI*16, dtb_w + (size_t)i*DI*16,
        dtf_b + (size_t)i*DI, dtb_b + (size_t)i*DI,
        A_logf + (size_t)i*DI*NSTATE, A_logb + (size_t)i*DI*NSTATE,
        Dsf + (size_t)i*DI, Dsb + (size_t)i*DI, Hcb, Yb);
    k_gemm_mfma<<<dim3(25, 4), 256, 0, stream>>>(Yb, Yb + nTok*DI,
        WoutB + (size_t)i*CC*DI, H, nullptr, nullptr, (int)nTok, CC, DI);
  }
  k_head<<<dim3(10), 256, 0, stream>>>(H, R, normf_w, bbox_w1, bbox_b1, bbox_w2, bbox_b2,
                                       pix_w1, pix_b1, pix_w2, pix_b2, out);
}